// Round 10
// baseline (1044.818 us; speedup 1.0000x reference)
//
#include <hip/hip_runtime.h>
#include <hip/hip_fp16.h>

#define D 64

// ---------------------------------------------------------------------------
// Software grid barrier: monotone device-scope counter (zeroed by k_init each
// call). Valid across non-coherent XCD L2s: __threadfence() = device-scope
// fence (writeback/invalidate), atomics resolve at the device coherent point
// (measured R5: atomics bypass local L2).
__device__ __forceinline__ void gbar(int* cnt, int goal) {
    __syncthreads();
    __threadfence();
    if (threadIdx.x == 0) {
        __hip_atomic_fetch_add(cnt, 1, __ATOMIC_ACQ_REL, __HIP_MEMORY_SCOPE_AGENT);
        while (__hip_atomic_load(cnt, __ATOMIC_ACQUIRE, __HIP_MEMORY_SCOPE_AGENT) < goal)
            __builtin_amdgcn_s_sleep(1);
    }
    __syncthreads();
    __threadfence();
}

__global__ __launch_bounds__(256) void k_init(int* __restrict__ cnt, int n, int* __restrict__ gb) {
    int i = blockIdx.x * blockDim.x + threadIdx.x;
    if (i == 0) *gb = 0;
    int stride = gridDim.x * blockDim.x;
    for (int j = i; j < n; j += stride) cnt[j] = 0;
}

// LDS union across phases (max 24 KB -> 6 blocks/CU).
struct FG1 { float Ws[D][D]; float Xs[16][D + 4]; };  // gemm1: padded Xs (b32 row reads)
struct FG2 { float Ws[D][D]; float Xs[32][D]; };      // gemm2: unpadded (broadcast b128 reads)
union SharedU { int scan[256]; FG1 f1; FG2 f2; };

__global__ __launch_bounds__(256) void k_mega(
    const int* __restrict__ src, const int* __restrict__ dst, int E, int N,
    const float* __restrict__ emb, const float* __restrict__ W1,
    const float* __restrict__ b1, const float* __restrict__ W2,
    const float* __restrict__ b2,
    int* __restrict__ cnt, int* __restrict__ rowptr, int* __restrict__ cursor,
    int* __restrict__ bsums, int* __restrict__ csr, float* __restrict__ dinv,
    __half* __restrict__ g1, float* __restrict__ x, __half* __restrict__ g2,
    float* __restrict__ out, int* gb) {
    __shared__ SharedU sh;
    const int nb = gridDim.x;
    const int tid = threadIdx.x;

    // ---- P1: degree histogram (8-way XCD partition: blockIdx&7 -> XCD)
    {
        int r = blockIdx.x & 7;
        int lo = (int)(((long long)r * N) >> 3);
        int hi = (int)(((long long)(r + 1) * N) >> 3);
        int nch = nb >> 3, chunk = blockIdx.x >> 3;
        for (int i = chunk * 256 + tid; i < E; i += nch * 256) {
            int d = dst[i];
            if (d >= lo && d < hi) atomicAdd(&cnt[d], 1);
        }
    }
    gbar(gb, nb);

    // ---- P2: per-2048-segment exclusive scan (partials + segment sums)
    int nseg1 = (N + 2047) / 2048;
    for (int seg = blockIdx.x; seg < nseg1; seg += nb) {
        int base = seg * 2048 + tid * 8;
        int v[8]; int s = 0;
#pragma unroll
        for (int j = 0; j < 8; ++j) {
            int idx = base + j;
            v[j] = (idx < N) ? cnt[idx] : 0;
            s += v[j];
        }
        sh.scan[tid] = s;
        __syncthreads();
        for (int off2 = 1; off2 < 256; off2 <<= 1) {
            int t = (tid >= off2) ? sh.scan[tid - off2] : 0;
            __syncthreads();
            sh.scan[tid] += t;
            __syncthreads();
        }
        int run = sh.scan[tid] - s;
#pragma unroll
        for (int j = 0; j < 8; ++j) {
            int idx = base + j;
            if (idx < N) rowptr[idx] = run;
            run += v[j];
        }
        if (tid == 255) bsums[seg] = sh.scan[255];
        __syncthreads();
    }
    gbar(gb, 2 * nb);

    // ---- P3: add segment offsets; emit cursor, dinv, rowptr[N]
    int nseg2 = (N + 255) / 256;
    for (int seg = blockIdx.x; seg < nseg2; seg += nb) {
        int i = seg * 256 + tid;
        int b = seg >> 3;  // 2048-super-segment index
        int off0 = 0;
        for (int j = 0; j < b; ++j) off0 += bsums[j];
        if (i < N) {
            int rp = rowptr[i] + off0;
            rowptr[i] = rp;
            cursor[i] = rp;
            dinv[i] = rsqrtf((float)(cnt[i] + 1));
        }
        if (seg == 0 && tid == 0) {
            int t = 0;
            for (int j = 0; j < nseg1; ++j) t += bsums[j];
            rowptr[N] = t;
        }
    }
    gbar(gb, 3 * nb);

    // ---- P4: CSR fill (blocks < half, XCD-partitioned) || gemm1 (rest)
    {
        int half = nb >> 1;
        if (blockIdx.x < half) {
            int r = blockIdx.x & 7;
            int lo = (int)(((long long)r * N) >> 3);
            int hi = (int)(((long long)(r + 1) * N) >> 3);
            int nch = half >> 3, chunk = blockIdx.x >> 3;
            for (int i = chunk * 256 + tid; i < E; i += nch * 256) {
                int d = dst[i];
                if (d >= lo && d < hi) {
                    int pos = atomicAdd(&cursor[d], 1);
                    csr[pos] = src[i];
                }
            }
        } else {
            int ngb = nb - half, gbk = blockIdx.x - half;
            int rl = tid >> 4, c4 = tid & 15;
            for (int i = tid; i < (D * D) / 4; i += 256)
                reinterpret_cast<float4*>(&sh.f1.Ws[0][0])[i] =
                    reinterpret_cast<const float4*>(W1)[i];
            int ntiles = (N + 15) / 16;
            for (int tile = gbk; tile < ntiles; tile += ngb) {
                int row = tile * 16 + rl;
                __syncthreads();  // covers Ws staging on first iter + Xs reuse
                float4 v = make_float4(0.f, 0.f, 0.f, 0.f);
                if (row < N) v = reinterpret_cast<const float4*>(emb)[(size_t)row * 16 + c4];
                *reinterpret_cast<float4*>(&sh.f1.Xs[rl][c4 * 4]) = v;
                __syncthreads();
                float4 acc = make_float4(0.f, 0.f, 0.f, 0.f);
#pragma unroll
                for (int k = 0; k < D; ++k) {
                    float xk = sh.f1.Xs[rl][k];
                    float4 w = *reinterpret_cast<const float4*>(&sh.f1.Ws[k][c4 * 4]);
                    acc.x += xk * w.x; acc.y += xk * w.y;
                    acc.z += xk * w.z; acc.w += xk * w.w;
                }
                if (row < N) {
                    float dv = dinv[row];
                    __half2 h01 = __floats2half2_rn(acc.x * dv, acc.y * dv);
                    __half2 h23 = __floats2half2_rn(acc.z * dv, acc.w * dv);
                    int2 p;
                    p.x = *reinterpret_cast<int*>(&h01);
                    p.y = *reinterpret_cast<int*>(&h23);
                    reinterpret_cast<int2*>(g1)[(size_t)row * 16 + c4] = p;
                }
            }
        }
    }
    gbar(gb, 4 * nb);

    // ---- P5: agg1 -> x fp32 (relu(. * dinv + b1)); no LDS, no block barriers
    {
        int wv = tid >> 6, lane = tid & 63, eq = lane >> 4, c4 = lane & 15;
        for (int wid = blockIdx.x * 4 + wv; wid < N; wid += nb * 4) {
            int beg = rowptr[wid], end = rowptr[wid + 1];
            float4 acc = make_float4(0.f, 0.f, 0.f, 0.f);
            for (int e = beg + eq; e < end; e += 4) {
                int s = __builtin_nontemporal_load(&csr[e]);
                int2 raw = reinterpret_cast<const int2*>(g1)[(size_t)s * 16 + c4];
                __half2 p0 = *reinterpret_cast<__half2*>(&raw.x);
                __half2 p1 = *reinterpret_cast<__half2*>(&raw.y);
                float2 f0 = __half22float2(p0), f1 = __half22float2(p1);
                acc.x += f0.x; acc.y += f0.y; acc.z += f1.x; acc.w += f1.y;
            }
#pragma unroll
            for (int off2 = 16; off2 < 64; off2 <<= 1) {
                acc.x += __shfl_xor(acc.x, off2);
                acc.y += __shfl_xor(acc.y, off2);
                acc.z += __shfl_xor(acc.z, off2);
                acc.w += __shfl_xor(acc.w, off2);
            }
            if (eq == 0) {
                int2 raw = reinterpret_cast<const int2*>(g1)[(size_t)wid * 16 + c4];
                __half2 p0 = *reinterpret_cast<__half2*>(&raw.x);
                __half2 p1 = *reinterpret_cast<__half2*>(&raw.y);
                float2 f0 = __half22float2(p0), f1 = __half22float2(p1);
                float dv = dinv[wid];
                float4 b4 = reinterpret_cast<const float4*>(b1)[c4];
                float4 o;
                o.x = fmaxf((acc.x + f0.x) * dv + b4.x, 0.f);
                o.y = fmaxf((acc.y + f0.y) * dv + b4.y, 0.f);
                o.z = fmaxf((acc.z + f1.x) * dv + b4.z, 0.f);
                o.w = fmaxf((acc.w + f1.y) * dv + b4.w, 0.f);
                reinterpret_cast<float4*>(x)[(size_t)wid * 16 + c4] = o;
            }
        }
    }
    gbar(gb, 5 * nb);

    // ---- P6: gemm2 (batched, W2 staged ONCE per persistent block; acc[8])
    {
        int col = tid & 63, rq = tid >> 6;
        for (int i = tid; i < (D * D) / 4; i += 256)
            reinterpret_cast<float4*>(&sh.f2.Ws[0][0])[i] =
                reinterpret_cast<const float4*>(W2)[i];
        int ntiles2 = (N + 31) / 32;
        for (int tile = blockIdx.x; tile < ntiles2; tile += nb) {
            int rowbase = tile * 32;
            __syncthreads();  // covers Ws staging on first iter + Xs reuse
            if (rowbase + 32 <= N) {
                const float4* xp = reinterpret_cast<const float4*>(x + (size_t)rowbase * D);
                for (int i = tid; i < (32 * D) / 4; i += 256)
                    reinterpret_cast<float4*>(&sh.f2.Xs[0][0])[i] = xp[i];
            } else {
                for (int i = tid; i < 32 * D; i += 256) {
                    int rr = rowbase + (i >> 6);
                    sh.f2.Xs[i >> 6][i & 63] = (rr < N) ? x[(size_t)rr * D + (i & 63)] : 0.f;
                }
            }
            __syncthreads();
            float accv[8];
#pragma unroll
            for (int j = 0; j < 8; ++j) accv[j] = 0.f;
#pragma unroll
            for (int k4 = 0; k4 < D; k4 += 4) {
                float w0 = sh.f2.Ws[k4 + 0][col];
                float w1 = sh.f2.Ws[k4 + 1][col];
                float w2v = sh.f2.Ws[k4 + 2][col];
                float w3 = sh.f2.Ws[k4 + 3][col];
#pragma unroll
                for (int j = 0; j < 8; ++j) {
                    float4 xv = *reinterpret_cast<const float4*>(&sh.f2.Xs[(rq << 3) + j][k4]);
                    accv[j] += xv.x * w0 + xv.y * w1 + xv.z * w2v + xv.w * w3;
                }
            }
#pragma unroll
            for (int j = 0; j < 8; ++j) {
                int rr = rowbase + (rq << 3) + j;
                if (rr < N) g2[(size_t)rr * D + col] = __float2half(accv[j] * dinv[rr]);
            }
        }
    }
    gbar(gb, 6 * nb);

    // ---- P7: agg2 -> out (+b2, no relu)
    {
        int wv = tid >> 6, lane = tid & 63, eq = lane >> 4, c4 = lane & 15;
        for (int wid = blockIdx.x * 4 + wv; wid < N; wid += nb * 4) {
            int beg = rowptr[wid], end = rowptr[wid + 1];
            float4 acc = make_float4(0.f, 0.f, 0.f, 0.f);
            for (int e = beg + eq; e < end; e += 4) {
                int s = __builtin_nontemporal_load(&csr[e]);
                int2 raw = reinterpret_cast<const int2*>(g2)[(size_t)s * 16 + c4];
                __half2 p0 = *reinterpret_cast<__half2*>(&raw.x);
                __half2 p1 = *reinterpret_cast<__half2*>(&raw.y);
                float2 f0 = __half22float2(p0), f1 = __half22float2(p1);
                acc.x += f0.x; acc.y += f0.y; acc.z += f1.x; acc.w += f1.y;
            }
#pragma unroll
            for (int off2 = 16; off2 < 64; off2 <<= 1) {
                acc.x += __shfl_xor(acc.x, off2);
                acc.y += __shfl_xor(acc.y, off2);
                acc.z += __shfl_xor(acc.z, off2);
                acc.w += __shfl_xor(acc.w, off2);
            }
            if (eq == 0) {
                int2 raw = reinterpret_cast<const int2*>(g2)[(size_t)wid * 16 + c4];
                __half2 p0 = *reinterpret_cast<__half2*>(&raw.x);
                __half2 p1 = *reinterpret_cast<__half2*>(&raw.y);
                float2 f0 = __half22float2(p0), f1 = __half22float2(p1);
                float dv = dinv[wid];
                float4 b4 = reinterpret_cast<const float4*>(b2)[c4];
                float4 o;
                o.x = (acc.x + f0.x) * dv + b4.x;
                o.y = (acc.y + f0.y) * dv + b4.y;
                o.z = (acc.z + f1.x) * dv + b4.z;
                o.w = (acc.w + f1.y) * dv + b4.w;
                reinterpret_cast<float4*>(out)[(size_t)wid * 16 + c4] = o;
            }
        }
    }
}

// ---------------- launch ----------------

extern "C" void kernel_launch(void* const* d_in, const int* in_sizes, int n_in,
                              void* d_out, int out_size, void* d_ws, size_t ws_size,
                              hipStream_t stream) {
    const int* ei = (const int*)d_in[0];
    const float* emb = (const float*)d_in[1];
    const float* W1 = (const float*)d_in[2];
    const float* b1 = (const float*)d_in[3];
    const float* W2 = (const float*)d_in[4];
    const float* b2 = (const float*)d_in[5];
    float* out = (float*)d_out;

    int E = in_sizes[0] / 2;
    int N = in_sizes[1] / D;
    const int* src = ei;
    const int* dst = ei + E;

    auto al = [](size_t v) { return (v + 255) & ~(size_t)255; };
    char* ws = (char*)d_ws;
    size_t off = 0;
    int* cnt = (int*)(ws + off);      off = al(off + (size_t)N * 4);
    int* rowptr = (int*)(ws + off);   off = al(off + ((size_t)N + 1) * 4);
    int* cursor = (int*)(ws + off);   off = al(off + (size_t)N * 4);
    int* bsums = (int*)(ws + off);    off = al(off + 64 * 4);
    int* csr = (int*)(ws + off);      off = al(off + (size_t)E * 4);
    float* dinv = (float*)(ws + off); off = al(off + (size_t)N * 4);
    __half* g1 = (__half*)(ws + off); off = al(off + (size_t)N * D * 2);
    float* x = (float*)(ws + off);    off = al(off + (size_t)N * D * 4);
    __half* g2 = (__half*)(ws + off); off = al(off + (size_t)N * D * 2);
    int* gb = (int*)(ws + off);       off = al(off + 256);

    // Occupancy-clamped persistent grid: guarantees co-residency for gbar.
    // Host-side queries only (no stream ops) -> graph-capture safe.
    int dev = 0;
    hipGetDevice(&dev);
    hipDeviceProp_t prop;
    hipGetDeviceProperties(&prop, dev);
    int maxb = 0;
    hipOccupancyMaxActiveBlocksPerMultiprocessor(&maxb, k_mega, 256, 0);
    if (maxb < 1) maxb = 1;
    if (maxb > 8) maxb = 8;
    int nb = maxb * prop.multiProcessorCount;
    nb &= ~15;            // multiple of 16 (8-way XCD partition of half-grid)
    if (nb < 64) nb = 64;
    if (nb > 2048) nb = 2048;

    hipLaunchKernelGGL(k_init, dim3(512), dim3(256), 0, stream, cnt, N, gb);
    hipLaunchKernelGGL(k_mega, dim3(nb), dim3(256), 0, stream,
                       src, dst, E, N, emb, W1, b1, W2, b2,
                       cnt, rowptr, cursor, bsums, csr, dinv, g1, x, g2, out, gb);
}

// Round 11
// 209.184 us; speedup vs baseline: 4.9947x; 4.9947x over previous
//
#include <hip/hip_runtime.h>
#include <hip/hip_fp16.h>

#define D 64

// ---------------- CSR build ----------------
// k_hist / fill partition the dst space 8 ways by blockIdx.x&7 (XCD-local
// line ownership; unpartitioned scatter measured 64B writeback per 4B store).

__global__ __launch_bounds__(256) void k_zero(int* __restrict__ p, int n4) {
    int stride = gridDim.x * blockDim.x;
    for (int i = blockIdx.x * blockDim.x + threadIdx.x; i < n4; i += stride)
        reinterpret_cast<int4*>(p)[i] = make_int4(0, 0, 0, 0);
}

__global__ __launch_bounds__(256) void k_hist(const int* __restrict__ dst,
                                              int* __restrict__ cnt, int e, int n) {
    int r = blockIdx.x & 7;
    int lo = (int)(((long long)r * n) >> 3);
    int hi = (int)(((long long)(r + 1) * n) >> 3);
    int nch = gridDim.x >> 3;
    int chunk = blockIdx.x >> 3;
    for (int i = chunk * blockDim.x + threadIdx.x; i < e; i += nch * blockDim.x) {
        int d = dst[i];
        if (d >= lo && d < hi) atomicAdd(&cnt[d], 1);
    }
}

__global__ void k_scan1(const int* __restrict__ cnt, int* __restrict__ rowptr,
                        int* __restrict__ bsums, int n) {
    __shared__ int lds[256];
    int tid = threadIdx.x;
    int base = blockIdx.x * 2048 + tid * 8;
    int v[8];
    int s = 0;
#pragma unroll
    for (int j = 0; j < 8; ++j) {
        int idx = base + j;
        v[j] = (idx < n) ? cnt[idx] : 0;
        s += v[j];
    }
    lds[tid] = s;
    __syncthreads();
    for (int off = 1; off < 256; off <<= 1) {
        int t = (tid >= off) ? lds[tid - off] : 0;
        __syncthreads();
        lds[tid] += t;
        __syncthreads();
    }
    int run = lds[tid] - s;
#pragma unroll
    for (int j = 0; j < 8; ++j) {
        int idx = base + j;
        if (idx < n) rowptr[idx] = run;
        run += v[j];
    }
    if (tid == 255) bsums[blockIdx.x] = lds[255];
}

__global__ void k_scan2(int* __restrict__ rowptr, int* __restrict__ cursor,
                        float* __restrict__ dinv, const int* __restrict__ cnt,
                        const int* __restrict__ bsums, int n, int nb) {
    __shared__ int s_off;
    int i = blockIdx.x * blockDim.x + threadIdx.x;
    int b = (blockIdx.x * blockDim.x) >> 11;
    if (threadIdx.x == 0) {
        int o = 0;
        for (int j = 0; j < b; ++j) o += bsums[j];
        s_off = o;
    }
    __syncthreads();
    if (i < n) {
        int rp = rowptr[i] + s_off;
        rowptr[i] = rp;
        cursor[i] = rp;
        dinv[i] = rsqrtf((float)(cnt[i] + 1));
    }
    if (blockIdx.x == 0 && threadIdx.x == 0) {
        int t = 0;
        for (int j = 0; j < nb; ++j) t += bsums[j];
        rowptr[n] = t;
    }
}

// ---------------- fused fill || gemm1 ----------------
__global__ __launch_bounds__(256) void k_fill_gemm(
    const int* __restrict__ src, const int* __restrict__ dst,
    int* __restrict__ cursor, int* __restrict__ csr, int e, int n,
    const float* __restrict__ X, const float* __restrict__ W,
    const float* __restrict__ dinv, __half* __restrict__ G,
    int ntiles, int fill_blocks) {
    __shared__ float Ws[D][D];
    __shared__ float Xs[16][D + 4];

    if (blockIdx.x < fill_blocks) {  // fill path (no LDS, no barriers)
        int r = blockIdx.x & 7;
        int lo = (int)(((long long)r * n) >> 3);
        int hi = (int)(((long long)(r + 1) * n) >> 3);
        int nch = fill_blocks >> 3;
        int chunk = blockIdx.x >> 3;
        for (int i = chunk * blockDim.x + threadIdx.x; i < e; i += nch * blockDim.x) {
            int d = dst[i];
            if (d >= lo && d < hi) {
                int pos = atomicAdd(&cursor[d], 1);
                csr[pos] = src[i];
            }
        }
        return;
    }

    int tid = threadIdx.x;
    int rl = tid >> 4;
    int c4 = tid & 15;
    int gb = blockIdx.x - fill_blocks;
    int ngb = gridDim.x - fill_blocks;

    for (int i = tid; i < (D * D) / 4; i += 256)
        reinterpret_cast<float4*>(&Ws[0][0])[i] = reinterpret_cast<const float4*>(W)[i];

    for (int tile = gb; tile < ntiles; tile += ngb) {
        int row = tile * 16 + rl;
        __syncthreads();
        {
            float4 v = make_float4(0.f, 0.f, 0.f, 0.f);
            if (row < n) v = reinterpret_cast<const float4*>(X)[(size_t)row * 16 + c4];
            *reinterpret_cast<float4*>(&Xs[rl][c4 * 4]) = v;
        }
        __syncthreads();

        float4 acc = make_float4(0.f, 0.f, 0.f, 0.f);
#pragma unroll
        for (int k = 0; k < D; ++k) {
            float xk = Xs[rl][k];
            float4 w = *reinterpret_cast<const float4*>(&Ws[k][c4 * 4]);
            acc.x += xk * w.x; acc.y += xk * w.y;
            acc.z += xk * w.z; acc.w += xk * w.w;
        }
        if (row < n) {
            float dv = dinv[row];
            __half2 h01 = __floats2half2_rn(acc.x * dv, acc.y * dv);
            __half2 h23 = __floats2half2_rn(acc.z * dv, acc.w * dv);
            int2 packed;
            packed.x = *reinterpret_cast<int*>(&h01);
            packed.y = *reinterpret_cast<int*>(&h23);
            reinterpret_cast<int2*>(G)[(size_t)row * 16 + c4] = packed;
        }
    }
}

// ---------------- agg1: gather + relu -> x (fp32, ws) ----------------
// Pure gather, no LDS. (R9's fused agg+gemm was LDS-issue-bound: 64 scalar
// Ws reads per output row. Batched gemm2b amortizes Ws reads 8x.)
__global__ __launch_bounds__(256) void k_agg1(const __half* __restrict__ G,
                                              const int* __restrict__ rowptr,
                                              const int* __restrict__ csr,
                                              const float* __restrict__ dinv,
                                              const float* __restrict__ bias,
                                              float* __restrict__ x, int n) {
    int wid = (blockIdx.x * blockDim.x + threadIdx.x) >> 6;
    if (wid >= n) return;
    int lane = threadIdx.x & 63;
    int eq = lane >> 4;
    int c4 = lane & 15;
    int beg = rowptr[wid];
    int end = rowptr[wid + 1];

    float4 acc = make_float4(0.f, 0.f, 0.f, 0.f);
    for (int e = beg + eq; e < end; e += 4) {
        int s = __builtin_nontemporal_load(&csr[e]);
        int2 raw = reinterpret_cast<const int2*>(G)[(size_t)s * 16 + c4];
        __half2 p0 = *reinterpret_cast<__half2*>(&raw.x);
        __half2 p1 = *reinterpret_cast<__half2*>(&raw.y);
        float2 f0 = __half22float2(p0);
        float2 f1 = __half22float2(p1);
        acc.x += f0.x; acc.y += f0.y; acc.z += f1.x; acc.w += f1.y;
    }
#pragma unroll
    for (int off = 16; off < 64; off <<= 1) {
        acc.x += __shfl_xor(acc.x, off);
        acc.y += __shfl_xor(acc.y, off);
        acc.z += __shfl_xor(acc.z, off);
        acc.w += __shfl_xor(acc.w, off);
    }
    if (eq == 0) {
        int2 raw = reinterpret_cast<const int2*>(G)[(size_t)wid * 16 + c4];
        __half2 p0 = *reinterpret_cast<__half2*>(&raw.x);
        __half2 p1 = *reinterpret_cast<__half2*>(&raw.y);
        float2 f0 = __half22float2(p0);
        float2 f1 = __half22float2(p1);
        float dv = dinv[wid];
        float4 b4 = reinterpret_cast<const float4*>(bias)[c4];
        float4 o;
        o.x = fmaxf((acc.x + f0.x) * dv + b4.x, 0.f);
        o.y = fmaxf((acc.y + f0.y) * dv + b4.y, 0.f);
        o.z = fmaxf((acc.z + f1.x) * dv + b4.z, 0.f);
        o.w = fmaxf((acc.w + f1.y) * dv + b4.w, 0.f);
        reinterpret_cast<float4*>(x)[(size_t)wid * 16 + c4] = o;
    }
}

// ---------------- gemm2b: batched x@W2 -> g2 fp16 (scaled) ----------------
// 32 rows/tile, acc[8]/thread: Ws LDS reads amortized over 8 output rows.
__global__ __launch_bounds__(256) void k_gemm2b(const float* __restrict__ X,
                                                const float* __restrict__ W,
                                                const float* __restrict__ dinv,
                                                __half* __restrict__ G, int n, int ntiles) {
    __shared__ float Ws[D][D];   // 16 KB
    __shared__ float Xs[32][D];  // 8 KB
    int tid = threadIdx.x;
    int col = tid & 63;
    int rq = tid >> 6;

    for (int i = tid; i < (D * D) / 4; i += 256)
        reinterpret_cast<float4*>(&Ws[0][0])[i] = reinterpret_cast<const float4*>(W)[i];

    for (int tile = blockIdx.x; tile < ntiles; tile += gridDim.x) {
        int rowbase = tile * 32;
        __syncthreads();  // Ws staged (first iter) / Xs consumed (later iters)
        if (rowbase + 32 <= n) {
            const float4* xp = reinterpret_cast<const float4*>(X + (size_t)rowbase * D);
            for (int i = tid; i < (32 * D) / 4; i += 256)
                reinterpret_cast<float4*>(&Xs[0][0])[i] = xp[i];
        } else {
            for (int i = tid; i < 32 * D; i += 256) {
                int r = rowbase + (i >> 6);
                Xs[i >> 6][i & 63] = (r < n) ? X[(size_t)r * D + (i & 63)] : 0.f;
            }
        }
        __syncthreads();

        float acc[8];
#pragma unroll
        for (int j = 0; j < 8; ++j) acc[j] = 0.f;
#pragma unroll
        for (int k4 = 0; k4 < D; k4 += 4) {
            float w0 = Ws[k4 + 0][col];
            float w1 = Ws[k4 + 1][col];
            float w2 = Ws[k4 + 2][col];
            float w3 = Ws[k4 + 3][col];
#pragma unroll
            for (int j = 0; j < 8; ++j) {
                float4 xv = *reinterpret_cast<const float4*>(&Xs[(rq << 3) + j][k4]);
                acc[j] += xv.x * w0 + xv.y * w1 + xv.z * w2 + xv.w * w3;
            }
        }
#pragma unroll
        for (int j = 0; j < 8; ++j) {
            int r = rowbase + (rq << 3) + j;
            if (r < n) G[(size_t)r * D + col] = __float2half(acc[j] * dinv[r]);
        }
    }
}

// ---------------- agg2 -> out ----------------
__global__ __launch_bounds__(256) void k_agg2(const __half* __restrict__ G,
                                              const int* __restrict__ rowptr,
                                              const int* __restrict__ csr,
                                              const float* __restrict__ dinv,
                                              const float* __restrict__ bias,
                                              float* __restrict__ out, int n) {
    int wid = (blockIdx.x * blockDim.x + threadIdx.x) >> 6;
    if (wid >= n) return;
    int lane = threadIdx.x & 63;
    int eq = lane >> 4;
    int c4 = lane & 15;
    int beg = rowptr[wid];
    int end = rowptr[wid + 1];

    float4 acc = make_float4(0.f, 0.f, 0.f, 0.f);
    for (int e = beg + eq; e < end; e += 4) {
        int s = __builtin_nontemporal_load(&csr[e]);
        int2 raw = reinterpret_cast<const int2*>(G)[(size_t)s * 16 + c4];
        __half2 p0 = *reinterpret_cast<__half2*>(&raw.x);
        __half2 p1 = *reinterpret_cast<__half2*>(&raw.y);
        float2 f0 = __half22float2(p0);
        float2 f1 = __half22float2(p1);
        acc.x += f0.x; acc.y += f0.y; acc.z += f1.x; acc.w += f1.y;
    }
#pragma unroll
    for (int off = 16; off < 64; off <<= 1) {
        acc.x += __shfl_xor(acc.x, off);
        acc.y += __shfl_xor(acc.y, off);
        acc.z += __shfl_xor(acc.z, off);
        acc.w += __shfl_xor(acc.w, off);
    }
    if (eq == 0) {
        int2 raw = reinterpret_cast<const int2*>(G)[(size_t)wid * 16 + c4];
        __half2 p0 = *reinterpret_cast<__half2*>(&raw.x);
        __half2 p1 = *reinterpret_cast<__half2*>(&raw.y);
        float2 f0 = __half22float2(p0);
        float2 f1 = __half22float2(p1);
        float dv = dinv[wid];
        float4 b4 = reinterpret_cast<const float4*>(bias)[c4];
        float4 o;
        o.x = (acc.x + f0.x) * dv + b4.x;
        o.y = (acc.y + f0.y) * dv + b4.y;
        o.z = (acc.z + f1.x) * dv + b4.z;
        o.w = (acc.w + f1.y) * dv + b4.w;
        reinterpret_cast<float4*>(out)[(size_t)wid * 16 + c4] = o;
    }
}

// ---------------- launch ----------------

extern "C" void kernel_launch(void* const* d_in, const int* in_sizes, int n_in,
                              void* d_out, int out_size, void* d_ws, size_t ws_size,
                              hipStream_t stream) {
    const int* ei = (const int*)d_in[0];
    const float* emb = (const float*)d_in[1];
    const float* W1 = (const float*)d_in[2];
    const float* b1 = (const float*)d_in[3];
    const float* W2 = (const float*)d_in[4];
    const float* b2 = (const float*)d_in[5];
    float* out = (float*)d_out;

    int E = in_sizes[0] / 2;
    int N = in_sizes[1] / D;
    const int* src = ei;
    const int* dst = ei + E;

    auto al = [](size_t v) { return (v + 255) & ~(size_t)255; };
    char* ws = (char*)d_ws;
    size_t off = 0;
    int* cnt = (int*)(ws + off);      off = al(off + (size_t)N * 4);
    int* rowptr = (int*)(ws + off);   off = al(off + ((size_t)N + 1) * 4);
    int* cursor = (int*)(ws + off);   off = al(off + (size_t)N * 4);
    int* bsums = (int*)(ws + off);    off = al(off + 64 * 4);
    int* csr = (int*)(ws + off);      off = al(off + (size_t)E * 4);
    float* dinv = (float*)(ws + off); off = al(off + (size_t)N * 4);
    __half* g1 = (__half*)(ws + off); off = al(off + (size_t)N * D * 2);
    float* x = (float*)(ws + off);    off = al(off + (size_t)N * D * 4);
    __half* g2 = (__half*)(ws + off); off = al(off + (size_t)N * D * 2);

    int nb_scan = (N + 2047) / 2048;
    int ntiles16 = (N + 15) / 16;
    int ntiles32 = (N + 31) / 32;
    int fill_blocks = 1024;
    int gemm_blocks = 1024;
    int row_blocks = (N + 3) / 4;

    hipLaunchKernelGGL(k_zero, dim3(512), dim3(256), 0, stream, cnt, (N + 3) / 4);
    hipLaunchKernelGGL(k_hist, dim3(1024), dim3(256), 0, stream, dst, cnt, E, N);
    hipLaunchKernelGGL(k_scan1, dim3(nb_scan), dim3(256), 0, stream, cnt, rowptr, bsums, N);
    hipLaunchKernelGGL(k_scan2, dim3((N + 255) / 256), dim3(256), 0, stream,
                       rowptr, cursor, dinv, cnt, bsums, N, nb_scan);
    hipLaunchKernelGGL(k_fill_gemm, dim3(fill_blocks + gemm_blocks), dim3(256), 0, stream,
                       src, dst, cursor, csr, E, N, emb, W1, dinv, g1, ntiles16, fill_blocks);
    hipLaunchKernelGGL(k_agg1, dim3(row_blocks), dim3(256), 0, stream,
                       g1, rowptr, csr, dinv, b1, x, N);
    hipLaunchKernelGGL(k_gemm2b, dim3(1024), dim3(256), 0, stream,
                       x, W2, dinv, g2, N, ntiles32);
    hipLaunchKernelGGL(k_agg2, dim3(row_blocks), dim3(256), 0, stream,
                       g2, rowptr, csr, dinv, b2, out, N);
}

// Round 12
// 183.368 us; speedup vs baseline: 5.6979x; 1.1408x over previous
//
#include <hip/hip_runtime.h>
#include <hip/hip_fp16.h>

#define D 64

// ---------------- CSR build ----------------
// k_hist / fill partition the dst space 8 ways by blockIdx.x&7 (XCD-local
// line ownership; unpartitioned scatter measured 64B writeback per 4B store).

__global__ __launch_bounds__(256) void k_zero(int* __restrict__ p, int n4) {
    int stride = gridDim.x * blockDim.x;
    for (int i = blockIdx.x * blockDim.x + threadIdx.x; i < n4; i += stride)
        reinterpret_cast<int4*>(p)[i] = make_int4(0, 0, 0, 0);
}

__global__ __launch_bounds__(256) void k_hist(const int* __restrict__ dst,
                                              int* __restrict__ cnt, int e, int n) {
    int r = blockIdx.x & 7;
    int lo = (int)(((long long)r * n) >> 3);
    int hi = (int)(((long long)(r + 1) * n) >> 3);
    int nch = gridDim.x >> 3;
    int chunk = blockIdx.x >> 3;
    for (int i = chunk * blockDim.x + threadIdx.x; i < e; i += nch * blockDim.x) {
        int d = dst[i];
        if (d >= lo && d < hi) atomicAdd(&cnt[d], 1);
    }
}

__global__ void k_scan1(const int* __restrict__ cnt, int* __restrict__ rowptr,
                        int* __restrict__ bsums, int n) {
    __shared__ int lds[256];
    int tid = threadIdx.x;
    int base = blockIdx.x * 2048 + tid * 8;
    int v[8];
    int s = 0;
#pragma unroll
    for (int j = 0; j < 8; ++j) {
        int idx = base + j;
        v[j] = (idx < n) ? cnt[idx] : 0;
        s += v[j];
    }
    lds[tid] = s;
    __syncthreads();
    for (int off = 1; off < 256; off <<= 1) {
        int t = (tid >= off) ? lds[tid - off] : 0;
        __syncthreads();
        lds[tid] += t;
        __syncthreads();
    }
    int run = lds[tid] - s;
#pragma unroll
    for (int j = 0; j < 8; ++j) {
        int idx = base + j;
        if (idx < n) rowptr[idx] = run;
        run += v[j];
    }
    if (tid == 255) bsums[blockIdx.x] = lds[255];
}

__global__ void k_scan2(int* __restrict__ rowptr, int* __restrict__ cursor,
                        float* __restrict__ dinv, const int* __restrict__ cnt,
                        const int* __restrict__ bsums, int n, int nb) {
    __shared__ int s_off;
    int i = blockIdx.x * blockDim.x + threadIdx.x;
    int b = (blockIdx.x * blockDim.x) >> 11;
    if (threadIdx.x == 0) {
        int o = 0;
        for (int j = 0; j < b; ++j) o += bsums[j];
        s_off = o;
    }
    __syncthreads();
    if (i < n) {
        int rp = rowptr[i] + s_off;
        rowptr[i] = rp;
        cursor[i] = rp;
        dinv[i] = rsqrtf((float)(cnt[i] + 1));
    }
    if (blockIdx.x == 0 && threadIdx.x == 0) {
        int t = 0;
        for (int j = 0; j < nb; ++j) t += bsums[j];
        rowptr[n] = t;
    }
}

// ---------------- fused fill || gemm1 ----------------
__global__ __launch_bounds__(256) void k_fill_gemm(
    const int* __restrict__ src, const int* __restrict__ dst,
    int* __restrict__ cursor, int* __restrict__ csr, int e, int n,
    const float* __restrict__ X, const float* __restrict__ W,
    const float* __restrict__ dinv, __half* __restrict__ G,
    int ntiles, int fill_blocks) {
    __shared__ float Ws[D][D];
    __shared__ float Xs[16][D + 4];

    if (blockIdx.x < fill_blocks) {  // fill path (no LDS, no barriers)
        int r = blockIdx.x & 7;
        int lo = (int)(((long long)r * n) >> 3);
        int hi = (int)(((long long)(r + 1) * n) >> 3);
        int nch = fill_blocks >> 3;
        int chunk = blockIdx.x >> 3;
        for (int i = chunk * blockDim.x + threadIdx.x; i < e; i += nch * blockDim.x) {
            int d = dst[i];
            if (d >= lo && d < hi) {
                int pos = atomicAdd(&cursor[d], 1);
                csr[pos] = src[i];
            }
        }
        return;
    }

    int tid = threadIdx.x;
    int rl = tid >> 4;
    int c4 = tid & 15;
    int gb = blockIdx.x - fill_blocks;
    int ngb = gridDim.x - fill_blocks;

    for (int i = tid; i < (D * D) / 4; i += 256)
        reinterpret_cast<float4*>(&Ws[0][0])[i] = reinterpret_cast<const float4*>(W)[i];

    for (int tile = gb; tile < ntiles; tile += ngb) {
        int row = tile * 16 + rl;
        __syncthreads();
        {
            float4 v = make_float4(0.f, 0.f, 0.f, 0.f);
            if (row < n) v = reinterpret_cast<const float4*>(X)[(size_t)row * 16 + c4];
            *reinterpret_cast<float4*>(&Xs[rl][c4 * 4]) = v;
        }
        __syncthreads();

        float4 acc = make_float4(0.f, 0.f, 0.f, 0.f);
#pragma unroll
        for (int k = 0; k < D; ++k) {
            float xk = Xs[rl][k];
            float4 w = *reinterpret_cast<const float4*>(&Ws[k][c4 * 4]);
            acc.x += xk * w.x; acc.y += xk * w.y;
            acc.z += xk * w.z; acc.w += xk * w.w;
        }
        if (row < n) {
            float dv = dinv[row];
            __half2 h01 = __floats2half2_rn(acc.x * dv, acc.y * dv);
            __half2 h23 = __floats2half2_rn(acc.z * dv, acc.w * dv);
            int2 packed;
            packed.x = *reinterpret_cast<int*>(&h01);
            packed.y = *reinterpret_cast<int*>(&h23);
            reinterpret_cast<int2*>(G)[(size_t)row * 16 + c4] = packed;
        }
    }
}

// ---------------- agg1: gather + relu -> x (fp32, ws) ----------------
__global__ __launch_bounds__(256) void k_agg1(const __half* __restrict__ G,
                                              const int* __restrict__ rowptr,
                                              const int* __restrict__ csr,
                                              const float* __restrict__ dinv,
                                              const float* __restrict__ bias,
                                              float* __restrict__ x, int n) {
    int wid = (blockIdx.x * blockDim.x + threadIdx.x) >> 6;
    if (wid >= n) return;
    int lane = threadIdx.x & 63;
    int eq = lane >> 4;
    int c4 = lane & 15;
    int beg = rowptr[wid];
    int end = rowptr[wid + 1];

    float4 acc = make_float4(0.f, 0.f, 0.f, 0.f);
    for (int e = beg + eq; e < end; e += 4) {
        int s = __builtin_nontemporal_load(&csr[e]);
        int2 raw = reinterpret_cast<const int2*>(G)[(size_t)s * 16 + c4];
        __half2 p0 = *reinterpret_cast<__half2*>(&raw.x);
        __half2 p1 = *reinterpret_cast<__half2*>(&raw.y);
        float2 f0 = __half22float2(p0);
        float2 f1 = __half22float2(p1);
        acc.x += f0.x; acc.y += f0.y; acc.z += f1.x; acc.w += f1.y;
    }
#pragma unroll
    for (int off = 16; off < 64; off <<= 1) {
        acc.x += __shfl_xor(acc.x, off);
        acc.y += __shfl_xor(acc.y, off);
        acc.z += __shfl_xor(acc.z, off);
        acc.w += __shfl_xor(acc.w, off);
    }
    if (eq == 0) {
        int2 raw = reinterpret_cast<const int2*>(G)[(size_t)wid * 16 + c4];
        __half2 p0 = *reinterpret_cast<__half2*>(&raw.x);
        __half2 p1 = *reinterpret_cast<__half2*>(&raw.y);
        float2 f0 = __half22float2(p0);
        float2 f1 = __half22float2(p1);
        float dv = dinv[wid];
        float4 b4 = reinterpret_cast<const float4*>(bias)[c4];
        float4 o;
        o.x = fmaxf((acc.x + f0.x) * dv + b4.x, 0.f);
        o.y = fmaxf((acc.y + f0.y) * dv + b4.y, 0.f);
        o.z = fmaxf((acc.z + f1.x) * dv + b4.z, 0.f);
        o.w = fmaxf((acc.w + f1.y) * dv + b4.w, 0.f);
        reinterpret_cast<float4*>(x)[(size_t)wid * 16 + c4] = o;
    }
}

// ---------------- gemm2b: batched x@W2 -> g2 fp16 (scaled) ----------------
// R11 post-mortem: compiler fully unrolled the K-loop and allocated 256 VGPR
// -> 8.5% occupancy, 50 us. Fix: cap allocation (4 waves/EU => <=128 VGPR)
// and bound the live set with a partial unroll.
__global__ __launch_bounds__(256, 4) void k_gemm2b(const float* __restrict__ X,
                                                   const float* __restrict__ W,
                                                   const float* __restrict__ dinv,
                                                   __half* __restrict__ G, int n, int ntiles) {
    __shared__ float Ws[D][D];   // 16 KB
    __shared__ float Xs[32][D];  // 8 KB
    int tid = threadIdx.x;
    int col = tid & 63;
    int rq = tid >> 6;

    for (int i = tid; i < (D * D) / 4; i += 256)
        reinterpret_cast<float4*>(&Ws[0][0])[i] = reinterpret_cast<const float4*>(W)[i];

    for (int tile = blockIdx.x; tile < ntiles; tile += gridDim.x) {
        int rowbase = tile * 32;
        __syncthreads();  // Ws staged (first iter) / Xs consumed (later iters)
        if (rowbase + 32 <= n) {
            const float4* xp = reinterpret_cast<const float4*>(X + (size_t)rowbase * D);
            for (int i = tid; i < (32 * D) / 4; i += 256)
                reinterpret_cast<float4*>(&Xs[0][0])[i] = xp[i];
        } else {
            for (int i = tid; i < 32 * D; i += 256) {
                int r = rowbase + (i >> 6);
                Xs[i >> 6][i & 63] = (r < n) ? X[(size_t)r * D + (i & 63)] : 0.f;
            }
        }
        __syncthreads();

        float acc[8];
#pragma unroll
        for (int j = 0; j < 8; ++j) acc[j] = 0.f;
#pragma unroll 4
        for (int k4 = 0; k4 < D; k4 += 4) {
            float w0 = Ws[k4 + 0][col];
            float w1 = Ws[k4 + 1][col];
            float w2 = Ws[k4 + 2][col];
            float w3 = Ws[k4 + 3][col];
#pragma unroll
            for (int j = 0; j < 8; ++j) {
                float4 xv = *reinterpret_cast<const float4*>(&Xs[(rq << 3) + j][k4]);
                acc[j] += xv.x * w0 + xv.y * w1 + xv.z * w2 + xv.w * w3;
            }
        }
#pragma unroll
        for (int j = 0; j < 8; ++j) {
            int r = rowbase + (rq << 3) + j;
            if (r < n) G[(size_t)r * D + col] = __float2half(acc[j] * dinv[r]);
        }
    }
}

// ---------------- agg2 -> out ----------------
__global__ __launch_bounds__(256) void k_agg2(const __half* __restrict__ G,
                                              const int* __restrict__ rowptr,
                                              const int* __restrict__ csr,
                                              const float* __restrict__ dinv,
                                              const float* __restrict__ bias,
                                              float* __restrict__ out, int n) {
    int wid = (blockIdx.x * blockDim.x + threadIdx.x) >> 6;
    if (wid >= n) return;
    int lane = threadIdx.x & 63;
    int eq = lane >> 4;
    int c4 = lane & 15;
    int beg = rowptr[wid];
    int end = rowptr[wid + 1];

    float4 acc = make_float4(0.f, 0.f, 0.f, 0.f);
    for (int e = beg + eq; e < end; e += 4) {
        int s = __builtin_nontemporal_load(&csr[e]);
        int2 raw = reinterpret_cast<const int2*>(G)[(size_t)s * 16 + c4];
        __half2 p0 = *reinterpret_cast<__half2*>(&raw.x);
        __half2 p1 = *reinterpret_cast<__half2*>(&raw.y);
        float2 f0 = __half22float2(p0);
        float2 f1 = __half22float2(p1);
        acc.x += f0.x; acc.y += f0.y; acc.z += f1.x; acc.w += f1.y;
    }
#pragma unroll
    for (int off = 16; off < 64; off <<= 1) {
        acc.x += __shfl_xor(acc.x, off);
        acc.y += __shfl_xor(acc.y, off);
        acc.z += __shfl_xor(acc.z, off);
        acc.w += __shfl_xor(acc.w, off);
    }
    if (eq == 0) {
        int2 raw = reinterpret_cast<const int2*>(G)[(size_t)wid * 16 + c4];
        __half2 p0 = *reinterpret_cast<__half2*>(&raw.x);
        __half2 p1 = *reinterpret_cast<__half2*>(&raw.y);
        float2 f0 = __half22float2(p0);
        float2 f1 = __half22float2(p1);
        float dv = dinv[wid];
        float4 b4 = reinterpret_cast<const float4*>(bias)[c4];
        float4 o;
        o.x = (acc.x + f0.x) * dv + b4.x;
        o.y = (acc.y + f0.y) * dv + b4.y;
        o.z = (acc.z + f1.x) * dv + b4.z;
        o.w = (acc.w + f1.y) * dv + b4.w;
        reinterpret_cast<float4*>(out)[(size_t)wid * 16 + c4] = o;
    }
}

// ---------------- launch ----------------

extern "C" void kernel_launch(void* const* d_in, const int* in_sizes, int n_in,
                              void* d_out, int out_size, void* d_ws, size_t ws_size,
                              hipStream_t stream) {
    const int* ei = (const int*)d_in[0];
    const float* emb = (const float*)d_in[1];
    const float* W1 = (const float*)d_in[2];
    const float* b1 = (const float*)d_in[3];
    const float* W2 = (const float*)d_in[4];
    const float* b2 = (const float*)d_in[5];
    float* out = (float*)d_out;

    int E = in_sizes[0] / 2;
    int N = in_sizes[1] / D;
    const int* src = ei;
    const int* dst = ei + E;

    auto al = [](size_t v) { return (v + 255) & ~(size_t)255; };
    char* ws = (char*)d_ws;
    size_t off = 0;
    int* cnt = (int*)(ws + off);      off = al(off + (size_t)N * 4);
    int* rowptr = (int*)(ws + off);   off = al(off + ((size_t)N + 1) * 4);
    int* cursor = (int*)(ws + off);   off = al(off + (size_t)N * 4);
    int* bsums = (int*)(ws + off);    off = al(off + 64 * 4);
    int* csr = (int*)(ws + off);      off = al(off + (size_t)E * 4);
    float* dinv = (float*)(ws + off); off = al(off + (size_t)N * 4);
    __half* g1 = (__half*)(ws + off); off = al(off + (size_t)N * D * 2);
    float* x = (float*)(ws + off);    off = al(off + (size_t)N * D * 4);
    __half* g2 = (__half*)(ws + off); off = al(off + (size_t)N * D * 2);

    int nb_scan = (N + 2047) / 2048;
    int ntiles16 = (N + 15) / 16;
    int ntiles32 = (N + 31) / 32;
    int fill_blocks = 1024;
    int gemm_blocks = 1024;
    int row_blocks = (N + 3) / 4;

    hipLaunchKernelGGL(k_zero, dim3(512), dim3(256), 0, stream, cnt, (N + 3) / 4);
    hipLaunchKernelGGL(k_hist, dim3(1024), dim3(256), 0, stream, dst, cnt, E, N);
    hipLaunchKernelGGL(k_scan1, dim3(nb_scan), dim3(256), 0, stream, cnt, rowptr, bsums, N);
    hipLaunchKernelGGL(k_scan2, dim3((N + 255) / 256), dim3(256), 0, stream,
                       rowptr, cursor, dinv, cnt, bsums, N, nb_scan);
    hipLaunchKernelGGL(k_fill_gemm, dim3(fill_blocks + gemm_blocks), dim3(256), 0, stream,
                       src, dst, cursor, csr, E, N, emb, W1, dinv, g1, ntiles16, fill_blocks);
    hipLaunchKernelGGL(k_agg1, dim3(row_blocks), dim3(256), 0, stream,
                       g1, rowptr, csr, dinv, b1, x, N);
    hipLaunchKernelGGL(k_gemm2b, dim3(1024), dim3(256), 0, stream,
                       x, W2, dinv, g2, N, ntiles32);
    hipLaunchKernelGGL(k_agg2, dim3(row_blocks), dim3(256), 0, stream,
                       g2, rowptr, csr, dinv, b2, out, N);
}